// Round 1
// baseline (587.720 us; speedup 1.0000x reference)
//
#include <hip/hip_runtime.h>
#include <hip/hip_bf16.h>

#define S_LEN 2048
#define D_DIM 1024
#define NHEAD 16
#define HDIM  64
#define BATCH 4
#define MROWS (BATCH*S_LEN)   /* 8192 */

typedef short bf16x8 __attribute__((ext_vector_type(8)));
typedef float f32x4  __attribute__((ext_vector_type(4)));
typedef unsigned short u16;

__device__ inline u16 f2bf(float f) {
  union { float f; unsigned u; } v; v.f = f;
  unsigned r = v.u + 0x7fff + ((v.u >> 16) & 1);   // RNE
  return (u16)(r >> 16);
}

__device__ inline void gload_lds16(const void* g, void* l) {
  __builtin_amdgcn_global_load_lds(
      (const __attribute__((address_space(1))) void*)g,
      (__attribute__((address_space(3))) void*)l, 16, 0, 0);
}

// ---------------- fp32 -> bf16 convert (vectorized) ----------------
__global__ void cvt_x_kernel(const float* __restrict__ x, u16* __restrict__ xb, int n4) {
  int i = blockIdx.x * 256 + threadIdx.x;
  if (i >= n4) return;
  float4 v = reinterpret_cast<const float4*>(x)[i];
  ushort4 o;
  o.x = f2bf(v.x); o.y = f2bf(v.y); o.z = f2bf(v.z); o.w = f2bf(v.w);
  reinterpret_cast<ushort4*>(xb)[i] = o;
}

// ---------------- weight transpose: W[K][N] fp32 -> Wt[N][K] bf16 ----------------
__global__ void transpose_w_kernel(const float* __restrict__ w, u16* __restrict__ wt) {
  __shared__ float t[32][33];
  int tx = threadIdx.x, ty = threadIdx.y;
  int n0 = blockIdx.x * 32, k0 = blockIdx.y * 32;
#pragma unroll
  for (int j = 0; j < 32; j += 8)
    t[ty + j][tx] = w[(size_t)(k0 + ty + j) * D_DIM + n0 + tx];
  __syncthreads();
#pragma unroll
  for (int j = 0; j < 32; j += 8)
    wt[(size_t)(n0 + ty + j) * D_DIM + k0 + tx] = f2bf(t[tx][ty + j]);
}

// ---------------- V transpose per head: V[b][s][h*64+d] -> Vt[bh][d][s] ----------------
__global__ void transpose_v_kernel(const u16* __restrict__ Vb, u16* __restrict__ Vt) {
  __shared__ u16 t[32][33];
  int tx = threadIdx.x, ty = threadIdx.y;
  int s0 = blockIdx.x * 32, d0 = blockIdx.y * 32, bh = blockIdx.z;
  int b = bh >> 4, h = bh & 15;
#pragma unroll
  for (int j = 0; j < 32; j += 8)
    t[ty + j][tx] = Vb[(size_t)(b * S_LEN + s0 + ty + j) * D_DIM + h * HDIM + d0 + tx];
  __syncthreads();
#pragma unroll
  for (int j = 0; j < 32; j += 8)
    Vt[(size_t)bh * HDIM * S_LEN + (size_t)(d0 + ty + j) * S_LEN + s0 + tx] = t[tx][ty + j];
}

// ---------------- bf16 GEMM: C[M][1024] = A[M][1024] * Bt[1024][1024]^T ----------------
// m97 structure: 128x128 tile, BK=32, 4 waves (2x2 of 64x64), global_load_lds w=16.
template <int EPI>  // 0: bf16 C, 1: fp32 C + bias
__global__ __launch_bounds__(256) void gemm_bt_kernel(
    const u16* __restrict__ A, const u16* __restrict__ Bt,
    void* __restrict__ Cv, const float* __restrict__ bias) {
  __shared__ u16 lA[128 * 32];
  __shared__ u16 lB[128 * 32];
  const int tid = threadIdx.x, wid = tid >> 6, lane = tid & 63;
  const int bm = blockIdx.y, bn = blockIdx.x;
  const int fr = lane & 15, fq = lane >> 4;
  const int r0 = wid * 32;
  const int srow = lane >> 2, scol = (lane & 3) * 8;
  const u16* gA = A + (size_t)(bm * 128 + r0 + srow) * 1024 + scol;
  const u16* gB = Bt + (size_t)(bn * 128 + r0 + srow) * 1024 + scol;
  u16* lA0 = &lA[r0 * 32];
  u16* lB0 = &lB[r0 * 32];

  f32x4 acc[4][4] = {};
  const int wm = (wid >> 1) * 64, wn = (wid & 1) * 64;

  for (int k0 = 0; k0 < 1024; k0 += 32) {
    gload_lds16(gA + k0,             lA0);
    gload_lds16(gA + k0 + 16 * 1024, lA0 + 16 * 32);
    gload_lds16(gB + k0,             lB0);
    gload_lds16(gB + k0 + 16 * 1024, lB0 + 16 * 32);
    __syncthreads();
    bf16x8 fa[4], fb[4];
#pragma unroll
    for (int i = 0; i < 4; i++) {
      fa[i] = *(const bf16x8*)&lA[(wm + i * 16 + fr) * 32 + fq * 8];
      fb[i] = *(const bf16x8*)&lB[(wn + i * 16 + fr) * 32 + fq * 8];
    }
#pragma unroll
    for (int i = 0; i < 4; i++)
#pragma unroll
      for (int j = 0; j < 4; j++)
        acc[i][j] = __builtin_amdgcn_mfma_f32_16x16x32_bf16(fa[i], fb[j], acc[i][j], 0, 0, 0);
    __syncthreads();
  }

#pragma unroll
  for (int i = 0; i < 4; i++)
#pragma unroll
    for (int j = 0; j < 4; j++)
#pragma unroll
      for (int r = 0; r < 4; r++) {
        int row = bm * 128 + wm + i * 16 + fq * 4 + r;
        int col = bn * 128 + wn + j * 16 + fr;
        if (EPI == 0) {
          ((u16*)Cv)[(size_t)row * 1024 + col] = f2bf(acc[i][j][r]);
        } else {
          ((float*)Cv)[(size_t)row * 1024 + col] = acc[i][j][r] + bias[col];
        }
      }
}

// ---------------- flash attention (causal), bf16 in/out ----------------
// grid (S/64, B*H), 4 waves; wave owns 16 query rows. 32-key tiles.
__global__ __launch_bounds__(256) void attn_kernel(
    const u16* __restrict__ Q, const u16* __restrict__ K,
    const u16* __restrict__ Vt, u16* __restrict__ O) {
  __shared__ u16 P[4][16 * 40];   // per-wave P buffer, row stride 40 (2-way banks)
  const int tid = threadIdx.x, wid = tid >> 6, lane = tid & 63;
  const int fr = lane & 15, fq = lane >> 4;
  const int qblk = blockIdx.x, bh = blockIdx.y;
  const int b = bh >> 4, h = bh & 15;
  const int q0 = qblk * 64 + wid * 16;

  const u16* Qrow = Q + (size_t)(b * S_LEN + q0 + fr) * D_DIM + h * HDIM;
  bf16x8 qf0 = *(const bf16x8*)(Qrow + fq * 8);
  bf16x8 qf1 = *(const bf16x8*)(Qrow + 32 + fq * 8);
  const u16* Kb = K + (size_t)b * S_LEN * D_DIM + h * HDIM;
  const u16* Vb = Vt + (size_t)bh * HDIM * S_LEN;
  u16* Pw = P[wid];

  f32x4 acc[4] = {};
  float m[4], l[4];
#pragma unroll
  for (int r = 0; r < 4; r++) { m[r] = -3.0e38f; l[r] = 0.f; }

  const int jend = q0 + 16;   // last tile containing key == q0+15
  for (int j0 = 0; j0 < jend; j0 += 32) {
    f32x4 s[2];
#pragma unroll
    for (int c = 0; c < 2; c++) {
      const u16* Krow = Kb + (size_t)(j0 + c * 16 + fr) * D_DIM;
      bf16x8 kf0 = *(const bf16x8*)(Krow + fq * 8);
      bf16x8 kf1 = *(const bf16x8*)(Krow + 32 + fq * 8);
      f32x4 z = {};
      z = __builtin_amdgcn_mfma_f32_16x16x32_bf16(qf0, kf0, z, 0, 0, 0);
      z = __builtin_amdgcn_mfma_f32_16x16x32_bf16(qf1, kf1, z, 0, 0, 0);
      s[c] = z;
    }
    // scale + causal mask (mask first -> same since -inf/8 = -inf; we use -3e38 sentinel)
    float mt[4];
#pragma unroll
    for (int r = 0; r < 4; r++) {
      int qidx = q0 + fq * 4 + r;
#pragma unroll
      for (int c = 0; c < 2; c++) {
        int kidx = j0 + c * 16 + fr;
        float v = s[c][r] * 0.125f;
        s[c][r] = (kidx > qidx) ? -3.0e38f : v;
      }
      mt[r] = fmaxf(s[0][r], s[1][r]);
    }
#pragma unroll
    for (int off = 1; off <= 8; off <<= 1)
#pragma unroll
      for (int r = 0; r < 4; r++)
        mt[r] = fmaxf(mt[r], __shfl_xor(mt[r], off));

    float rs[4];
#pragma unroll
    for (int r = 0; r < 4; r++) {
      float mn = fmaxf(m[r], mt[r]);
      float sc = __expf(m[r] - mn);
      m[r] = mn;
      float p0 = __expf(s[0][r] - mn);
      float p1 = __expf(s[1][r] - mn);
      s[0][r] = p0; s[1][r] = p1;
      rs[r] = p0 + p1;
      l[r] *= sc;
#pragma unroll
      for (int d = 0; d < 4; d++) acc[d][r] *= sc;
    }
#pragma unroll
    for (int off = 1; off <= 8; off <<= 1)
#pragma unroll
      for (int r = 0; r < 4; r++)
        rs[r] += __shfl_xor(rs[r], off);
#pragma unroll
    for (int r = 0; r < 4; r++) l[r] += rs[r];

    // P (f32, D-layout) -> LDS bf16 -> reread as A-frag. Wave-private: DS in-order, no barrier.
#pragma unroll
    for (int c = 0; c < 2; c++)
#pragma unroll
      for (int r = 0; r < 4; r++)
        Pw[(fq * 4 + r) * 40 + c * 16 + fr] = f2bf(s[c][r]);
    bf16x8 pf = *(const bf16x8*)&Pw[fr * 40 + fq * 8];
#pragma unroll
    for (int d = 0; d < 4; d++) {
      bf16x8 vf = *(const bf16x8*)(Vb + (size_t)(d * 16 + fr) * S_LEN + j0 + fq * 8);
      acc[d] = __builtin_amdgcn_mfma_f32_16x16x32_bf16(pf, vf, acc[d], 0, 0, 0);
    }
  }

#pragma unroll
  for (int d = 0; d < 4; d++)
#pragma unroll
    for (int r = 0; r < 4; r++) {
      float o = acc[d][r] / l[r];
      O[(size_t)(b * S_LEN + q0 + fq * 4 + r) * D_DIM + h * HDIM + d * 16 + fr] = f2bf(o);
    }
}

// ---------------- launcher ----------------
extern "C" void kernel_launch(void* const* d_in, const int* in_sizes, int n_in,
                              void* d_out, int out_size, void* d_ws, size_t ws_size,
                              hipStream_t stream) {
  const float* x  = (const float*)d_in[0];
  const float* wq = (const float*)d_in[1];
  const float* wk = (const float*)d_in[2];
  const float* wv = (const float*)d_in[3];
  const float* wo = (const float*)d_in[4];
  const float* ob = (const float*)d_in[5];
  float* out = (float*)d_out;

  char* ws = (char*)d_ws;
  const size_t SZ = (size_t)MROWS * D_DIM * 2;   // 16 MiB per bf16 tensor
  u16* Xb  = (u16*)(ws);
  u16* Qb  = (u16*)(ws + SZ);
  u16* Kb  = (u16*)(ws + 2 * SZ);
  u16* Vbf = (u16*)(ws + 3 * SZ);
  u16* Vt  = (u16*)(ws + 4 * SZ);
  u16* Ab  = (u16*)(ws + 5 * SZ);
  u16* WqT = (u16*)(ws + 6 * SZ);
  u16* WkT = WqT + 1024 * 1024;
  u16* WvT = WkT + 1024 * 1024;
  u16* WoT = WvT + 1024 * 1024;

  cvt_x_kernel<<<(MROWS * D_DIM / 4) / 256, 256, 0, stream>>>(x, Xb, MROWS * D_DIM / 4);

  dim3 tb(32, 8);
  transpose_w_kernel<<<dim3(32, 32), tb, 0, stream>>>(wq, WqT);
  transpose_w_kernel<<<dim3(32, 32), tb, 0, stream>>>(wk, WkT);
  transpose_w_kernel<<<dim3(32, 32), tb, 0, stream>>>(wv, WvT);
  transpose_w_kernel<<<dim3(32, 32), tb, 0, stream>>>(wo, WoT);

  dim3 gg(1024 / 128, MROWS / 128);
  gemm_bt_kernel<0><<<gg, 256, 0, stream>>>(Xb, WqT, Qb, nullptr);
  gemm_bt_kernel<0><<<gg, 256, 0, stream>>>(Xb, WkT, Kb, nullptr);
  gemm_bt_kernel<0><<<gg, 256, 0, stream>>>(Xb, WvT, Vbf, nullptr);

  transpose_v_kernel<<<dim3(S_LEN / 32, HDIM / 32, BATCH * NHEAD), tb, 0, stream>>>(Vbf, Vt);

  attn_kernel<<<dim3(S_LEN / 64, BATCH * NHEAD), 256, 0, stream>>>(Qb, Kb, Vt, Ab);

  gemm_bt_kernel<1><<<gg, 256, 0, stream>>>(Ab, WoT, out, ob);
}

// Round 2
// 253.998 us; speedup vs baseline: 2.3139x; 2.3139x over previous
//
#include <hip/hip_runtime.h>
#include <hip/hip_bf16.h>

#define S_LEN 2048
#define D_DIM 1024
#define NHEAD 16
#define HDIM  64
#define BATCH 4
#define MROWS (BATCH*S_LEN)   /* 8192 */
#define QKV_LD 3072

typedef short bf16x8 __attribute__((ext_vector_type(8)));
typedef float f32x4  __attribute__((ext_vector_type(4)));
typedef float f32x16 __attribute__((ext_vector_type(16)));
typedef unsigned short u16;

#if __has_builtin(__builtin_amdgcn_exp2f)
#define EXP2(x) __builtin_amdgcn_exp2f(x)
#else
#define EXP2(x) __expf((x) * 0.6931471805599453f)
#endif

__device__ inline u16 f2bf(float f) {
  union { float f; unsigned u; } v; v.f = f;
  unsigned r = v.u + 0x7fff + ((v.u >> 16) & 1);   // RNE
  return (u16)(r >> 16);
}

__device__ inline unsigned cvtpk(float lo, float hi_) {
  unsigned d;
  asm("v_cvt_pk_bf16_f32 %0, %1, %2" : "=v"(d) : "v"(lo), "v"(hi_));
  return d;
}

__device__ inline void perm32swap(unsigned& a, unsigned& b) {
  asm volatile("v_permlane32_swap_b32 %0, %1" : "+v"(a), "+v"(b));
}

__device__ inline void gload_lds16(const void* g, void* l) {
  __builtin_amdgcn_global_load_lds(
      (const __attribute__((address_space(1))) void*)g,
      (__attribute__((address_space(3))) void*)l, 16, 0, 0);
}

// ---------------- fp32 -> bf16 convert (vectorized) ----------------
__global__ void cvt_x_kernel(const float* __restrict__ x, u16* __restrict__ xb, int n4) {
  int i = blockIdx.x * 256 + threadIdx.x;
  if (i >= n4) return;
  float4 v = reinterpret_cast<const float4*>(x)[i];
  ushort4 o;
  o.x = f2bf(v.x); o.y = f2bf(v.y); o.z = f2bf(v.z); o.w = f2bf(v.w);
  reinterpret_cast<ushort4*>(xb)[i] = o;
}

// ---------------- weight transpose: W[K][N] fp32 -> Wt[N][K] bf16 ----------------
__global__ void transpose_w_kernel(const float* __restrict__ w, u16* __restrict__ wt) {
  __shared__ float t[32][33];
  int tx = threadIdx.x, ty = threadIdx.y;
  int n0 = blockIdx.x * 32, k0 = blockIdx.y * 32;
#pragma unroll
  for (int j = 0; j < 32; j += 8)
    t[ty + j][tx] = w[(size_t)(k0 + ty + j) * D_DIM + n0 + tx];
  __syncthreads();
#pragma unroll
  for (int j = 0; j < 32; j += 8)
    wt[(size_t)(n0 + ty + j) * D_DIM + k0 + tx] = f2bf(t[tx][ty + j]);
}

// ---------------- V transpose per head: QKV[b][s][2048+h*64+d] -> Vt[bh][d][s] ----------------
__global__ void transpose_v_kernel(const u16* __restrict__ Vsrc, u16* __restrict__ Vt) {
  __shared__ u16 t[32][33];
  int tx = threadIdx.x, ty = threadIdx.y;
  int s0 = blockIdx.x * 32, d0 = blockIdx.y * 32, bh = blockIdx.z;
  int b = bh >> 4, h = bh & 15;
#pragma unroll
  for (int j = 0; j < 32; j += 8)
    t[ty + j][tx] = Vsrc[(size_t)(b * S_LEN + s0 + ty + j) * QKV_LD + h * HDIM + d0 + tx];
  __syncthreads();
#pragma unroll
  for (int j = 0; j < 32; j += 8)
    Vt[(size_t)bh * HDIM * S_LEN + (size_t)(d0 + ty + j) * S_LEN + s0 + tx] = t[tx][ty + j];
}

// ---------------- bf16 GEMM: C[M][ldc] = A[M][1024] * Bt[N][1024]^T ----------------
template <int EPI>  // 0: bf16 C, 1: fp32 C + bias
__global__ __launch_bounds__(256) void gemm_bt_kernel(
    const u16* __restrict__ A, const u16* __restrict__ Bt,
    void* __restrict__ Cv, const float* __restrict__ bias, int ldc) {
  __shared__ u16 lA[128 * 32];
  __shared__ u16 lB[128 * 32];
  const int tid = threadIdx.x, wid = tid >> 6, lane = tid & 63;
  const int bm = blockIdx.y, bn = blockIdx.x;
  const int fr = lane & 15, fq = lane >> 4;
  const int r0 = wid * 32;
  const int srow = lane >> 2, scol = (lane & 3) * 8;
  const u16* gA = A + (size_t)(bm * 128 + r0 + srow) * 1024 + scol;
  const u16* gB = Bt + (size_t)(bn * 128 + r0 + srow) * 1024 + scol;
  u16* lA0 = &lA[r0 * 32];
  u16* lB0 = &lB[r0 * 32];

  f32x4 acc[4][4] = {};
  const int wm = (wid >> 1) * 64, wn = (wid & 1) * 64;

  for (int k0 = 0; k0 < 1024; k0 += 32) {
    gload_lds16(gA + k0,             lA0);
    gload_lds16(gA + k0 + 16 * 1024, lA0 + 16 * 32);
    gload_lds16(gB + k0,             lB0);
    gload_lds16(gB + k0 + 16 * 1024, lB0 + 16 * 32);
    __syncthreads();
    bf16x8 fa[4], fb[4];
#pragma unroll
    for (int i = 0; i < 4; i++) {
      fa[i] = *(const bf16x8*)&lA[(wm + i * 16 + fr) * 32 + fq * 8];
      fb[i] = *(const bf16x8*)&lB[(wn + i * 16 + fr) * 32 + fq * 8];
    }
#pragma unroll
    for (int i = 0; i < 4; i++)
#pragma unroll
      for (int j = 0; j < 4; j++)
        acc[i][j] = __builtin_amdgcn_mfma_f32_16x16x32_bf16(fa[i], fb[j], acc[i][j], 0, 0, 0);
    __syncthreads();
  }

#pragma unroll
  for (int i = 0; i < 4; i++)
#pragma unroll
    for (int j = 0; j < 4; j++)
#pragma unroll
      for (int r = 0; r < 4; r++) {
        int row = bm * 128 + wm + i * 16 + fq * 4 + r;
        int col = bn * 128 + wn + j * 16 + fr;
        if (EPI == 0) {
          ((u16*)Cv)[(size_t)row * ldc + col] = f2bf(acc[i][j][r]);
        } else {
          ((float*)Cv)[(size_t)row * ldc + col] = acc[i][j][r] + bias[col];
        }
      }
}

// ---------------- flash attention (causal), swapped-operand 32x32 MFMA ----------------
// 4 waves/block, wave owns 32 q rows; KV tiles of 32. No LDS; K/V from L2.
// S^T = mfma(Kfrag, Qfrag): lane holds q=lane&31 (one row), k=(reg&3)+8*(reg>>2)+4*hi.
// O^T = mfma(Vtfrag, Pfrag): col=q stays lane-local -> softmax state needs no broadcasts.
__global__ __launch_bounds__(256) void attn_kernel(
    const u16* __restrict__ QKV, const u16* __restrict__ Vt, u16* __restrict__ O) {
  const int tid = threadIdx.x, wid = tid >> 6, lane = tid & 63;
  const int lq = lane & 31, hi = lane >> 5;
  // block swizzle: cluster each head on one XCD, spread qblks across CUs, big tiles first
  int f = blockIdx.x;
  int xcd = f & 7, kk = f >> 3;
  int bh = xcd * 8 + (kk & 7);
  int qblk = 15 - (kk >> 3);
  int b = bh >> 4, h = bh & 15;
  int q0 = qblk * 128 + wid * 32;
  int q = q0 + lq;

  const u16* Qrow = QKV + (size_t)(b * S_LEN + q) * QKV_LD + h * HDIM;
  bf16x8 qf[4];
#pragma unroll
  for (int s = 0; s < 4; s++)
    qf[s] = *(const bf16x8*)(Qrow + s * 16 + hi * 8);

  const u16* Kb = QKV + (size_t)b * S_LEN * QKV_LD + 1024 + h * HDIM;
  const u16* Vb = Vt + (size_t)bh * HDIM * S_LEN;

  f32x16 acc0 = {}, acc1 = {};
  float m = -3.0e38f, l = 0.f;
  const int nt = qblk * 4 + wid + 1;

  for (int t = 0; t < nt; ++t) {
    const int j0 = t * 32;
    const u16* Krow = Kb + (size_t)(j0 + lq) * QKV_LD;
    bf16x8 kf[4];
#pragma unroll
    for (int s = 0; s < 4; s++)
      kf[s] = *(const bf16x8*)(Krow + s * 16 + hi * 8);

    f32x16 sa = {};
#pragma unroll
    for (int s = 0; s < 4; s++)
      sa = __builtin_amdgcn_mfma_f32_32x32x16_bf16(kf[s], qf[s], sa, 0, 0, 0);

    // log2-domain scores: v = S * (1/8 * log2(e))
    float p[16];
#pragma unroll
    for (int r = 0; r < 16; ++r) p[r] = sa[r] * 0.1803368801f;

    if (t == nt - 1) {  // diagonal tile: causal mask
#pragma unroll
      for (int r = 0; r < 16; ++r) {
        int kidx = j0 + (r & 3) + 8 * (r >> 2) + 4 * hi;
        if (kidx > q) p[r] = -3.0e38f;
      }
    }

    // row max: 16 regs tree + one cross-half exchange
    float x8[8], x4[4], x2[2];
#pragma unroll
    for (int i = 0; i < 8; ++i) x8[i] = fmaxf(p[2 * i], p[2 * i + 1]);
#pragma unroll
    for (int i = 0; i < 4; ++i) x4[i] = fmaxf(x8[2 * i], x8[2 * i + 1]);
    x2[0] = fmaxf(x4[0], x4[1]); x2[1] = fmaxf(x4[2], x4[3]);
    float pm = fmaxf(x2[0], x2[1]);
    pm = fmaxf(pm, __shfl_xor(pm, 32));

    // defer-max (THR = 8 nats = 11.54 log2 units)
    if (__any(pm > m + 11.5f)) {
      float mn = fmaxf(m, pm);
      float sc = EXP2(m - mn);
      l *= sc;
#pragma unroll
      for (int r = 0; r < 16; ++r) { acc0[r] *= sc; acc1[r] *= sc; }
      m = mn;
    }

    float rs = 0.f;
#pragma unroll
    for (int r = 0; r < 16; ++r) { p[r] = EXP2(p[r] - m); rs += p[r]; }
    rs += __shfl_xor(rs, 32);
    l += rs;

    // pack P -> bf16 B-frags: cvt_pk pairs + permlane32 half-swaps
    unsigned c0 = cvtpk(p[0],  p[1]),  c1 = cvtpk(p[2],  p[3]);
    unsigned c2 = cvtpk(p[4],  p[5]),  c3 = cvtpk(p[6],  p[7]);
    unsigned c4 = cvtpk(p[8],  p[9]),  c5 = cvtpk(p[10], p[11]);
    unsigned c6 = cvtpk(p[12], p[13]), c7 = cvtpk(p[14], p[15]);
    perm32swap(c0, c2); perm32swap(c1, c3);
    perm32swap(c4, c6); perm32swap(c5, c7);
    union U4 { unsigned u[4]; bf16x8 v; } F0, F1;
    F0.u[0] = c0; F0.u[1] = c1; F0.u[2] = c2; F0.u[3] = c3;
    F1.u[0] = c4; F1.u[1] = c5; F1.u[2] = c6; F1.u[3] = c7;

    const u16* Vr0 = Vb + (size_t)lq * S_LEN + j0 + hi * 8;
    const u16* Vr1 = Vb + (size_t)(32 + lq) * S_LEN + j0 + hi * 8;
    bf16x8 vf00 = *(const bf16x8*)(Vr0);
    bf16x8 vf01 = *(const bf16x8*)(Vr0 + 16);
    bf16x8 vf10 = *(const bf16x8*)(Vr1);
    bf16x8 vf11 = *(const bf16x8*)(Vr1 + 16);
    acc0 = __builtin_amdgcn_mfma_f32_32x32x16_bf16(vf00, F0.v, acc0, 0, 0, 0);
    acc0 = __builtin_amdgcn_mfma_f32_32x32x16_bf16(vf01, F1.v, acc0, 0, 0, 0);
    acc1 = __builtin_amdgcn_mfma_f32_32x32x16_bf16(vf10, F0.v, acc1, 0, 0, 0);
    acc1 = __builtin_amdgcn_mfma_f32_32x32x16_bf16(vf11, F1.v, acc1, 0, 0, 0);
  }

  float inv = 1.f / l;
  u16* Orow = O + (size_t)(b * S_LEN + q) * D_DIM + h * HDIM;
#pragma unroll
  for (int g = 0; g < 4; ++g) {
    ushort4 o4;
    o4.x = f2bf(acc0[g * 4 + 0] * inv);
    o4.y = f2bf(acc0[g * 4 + 1] * inv);
    o4.z = f2bf(acc0[g * 4 + 2] * inv);
    o4.w = f2bf(acc0[g * 4 + 3] * inv);
    *(ushort4*)(Orow + 8 * g + 4 * hi) = o4;
  }
#pragma unroll
  for (int g = 0; g < 4; ++g) {
    ushort4 o4;
    o4.x = f2bf(acc1[g * 4 + 0] * inv);
    o4.y = f2bf(acc1[g * 4 + 1] * inv);
    o4.z = f2bf(acc1[g * 4 + 2] * inv);
    o4.w = f2bf(acc1[g * 4 + 3] * inv);
    *(ushort4*)(Orow + 32 + 8 * g + 4 * hi) = o4;
  }
}

// ---------------- launcher ----------------
extern "C" void kernel_launch(void* const* d_in, const int* in_sizes, int n_in,
                              void* d_out, int out_size, void* d_ws, size_t ws_size,
                              hipStream_t stream) {
  const float* x  = (const float*)d_in[0];
  const float* wq = (const float*)d_in[1];
  const float* wk = (const float*)d_in[2];
  const float* wv = (const float*)d_in[3];
  const float* wo = (const float*)d_in[4];
  const float* ob = (const float*)d_in[5];
  float* out = (float*)d_out;

  char* ws = (char*)d_ws;
  u16* Xb    = (u16*)(ws);                              // 16 MB
  u16* QKV   = (u16*)(ws + (size_t)16 * 1024 * 1024);   // 48 MB
  u16* Vtb   = (u16*)(ws + (size_t)64 * 1024 * 1024);   // 16 MB
  u16* Ab    = (u16*)(ws + (size_t)80 * 1024 * 1024);   // 16 MB
  u16* WqkvT = (u16*)(ws + (size_t)96 * 1024 * 1024);   // 6 MB (Wq;Wk;Wv rows)
  u16* WoT   = (u16*)(ws + (size_t)102 * 1024 * 1024);  // 2 MB

  cvt_x_kernel<<<(MROWS * D_DIM / 4) / 256, 256, 0, stream>>>(x, Xb, MROWS * D_DIM / 4);

  dim3 tb(32, 8);
  transpose_w_kernel<<<dim3(32, 32), tb, 0, stream>>>(wq, WqkvT);
  transpose_w_kernel<<<dim3(32, 32), tb, 0, stream>>>(wk, WqkvT + 1024 * 1024);
  transpose_w_kernel<<<dim3(32, 32), tb, 0, stream>>>(wv, WqkvT + 2 * 1024 * 1024);
  transpose_w_kernel<<<dim3(32, 32), tb, 0, stream>>>(wo, WoT);

  // fused QKV projection: [8192,1024] x [1024,3072] -> QKV [8192,3072]
  gemm_bt_kernel<0><<<dim3(QKV_LD / 128, MROWS / 128), 256, 0, stream>>>(
      Xb, WqkvT, QKV, nullptr, QKV_LD);

  transpose_v_kernel<<<dim3(S_LEN / 32, HDIM / 32, BATCH * NHEAD), tb, 0, stream>>>(
      QKV + 2048, Vtb);

  attn_kernel<<<dim3(1024), 256, 0, stream>>>(QKV, Vtb, Ab);

  gemm_bt_kernel<1><<<dim3(D_DIM / 128, MROWS / 128), 256, 0, stream>>>(
      Ab, WoT, out, ob, D_DIM);
}

// Round 3
// 186.965 us; speedup vs baseline: 3.1435x; 1.3585x over previous
//
#include <hip/hip_runtime.h>
#include <hip/hip_bf16.h>

#define S_LEN 2048
#define D_DIM 1024
#define NHEAD 16
#define HDIM  64
#define BATCH 4
#define MROWS (BATCH*S_LEN)   /* 8192 */
#define QKV_LD 3072

typedef short bf16x8 __attribute__((ext_vector_type(8)));
typedef float f32x4  __attribute__((ext_vector_type(4)));
typedef float f32x16 __attribute__((ext_vector_type(16)));
typedef unsigned short u16;

#if __has_builtin(__builtin_amdgcn_exp2f)
#define EXP2(x) __builtin_amdgcn_exp2f(x)
#else
#define EXP2(x) __expf((x) * 0.6931471805599453f)
#endif

__device__ inline u16 f2bf(float f) {
  union { float f; unsigned u; } v; v.f = f;
  unsigned r = v.u + 0x7fff + ((v.u >> 16) & 1);   // RNE
  return (u16)(r >> 16);
}

__device__ inline unsigned cvtpk(float lo, float hi_) {
  unsigned d;
  asm("v_cvt_pk_bf16_f32 %0, %1, %2" : "=v"(d) : "v"(lo), "v"(hi_));
  return d;
}

__device__ inline void perm32swap(unsigned& a, unsigned& b) {
  asm volatile("v_permlane32_swap_b32 %0, %1" : "+v"(a), "+v"(b));
}

__device__ inline void gload_lds16(const void* g, void* l) {
  __builtin_amdgcn_global_load_lds(
      (const __attribute__((address_space(1))) void*)g,
      (__attribute__((address_space(3))) void*)l, 16, 0, 0);
}

// ---------------- fp32 -> bf16 convert (vectorized) ----------------
__global__ void cvt_x_kernel(const float* __restrict__ x, u16* __restrict__ xb, int n4) {
  int i = blockIdx.x * 256 + threadIdx.x;
  if (i >= n4) return;
  float4 v = reinterpret_cast<const float4*>(x)[i];
  ushort4 o;
  o.x = f2bf(v.x); o.y = f2bf(v.y); o.z = f2bf(v.z); o.w = f2bf(v.w);
  reinterpret_cast<ushort4*>(xb)[i] = o;
}

// ---------------- weight transpose: W[K][N] fp32 -> Wt[N][K] bf16 ----------------
__global__ void transpose_w_kernel(const float* __restrict__ w, u16* __restrict__ wt) {
  __shared__ float t[32][33];
  int tx = threadIdx.x, ty = threadIdx.y;
  int n0 = blockIdx.x * 32, k0 = blockIdx.y * 32;
#pragma unroll
  for (int j = 0; j < 32; j += 8)
    t[ty + j][tx] = w[(size_t)(k0 + ty + j) * D_DIM + n0 + tx];
  __syncthreads();
#pragma unroll
  for (int j = 0; j < 32; j += 8)
    wt[(size_t)(n0 + ty + j) * D_DIM + k0 + tx] = f2bf(t[tx][ty + j]);
}

// ---------------- K fragment-pack: KP[((bh*64+j)*4+s)*64+lane] = lane's bf16x8 ----------------
// Matches QK A-frag: row = j*32 + (lane&31), elems = s*16 + (lane>>5)*8 .. +8 of head dh.
__global__ __launch_bounds__(256) void pack_k_kernel(const u16* __restrict__ QKV,
                                                     u16* __restrict__ KP) {
  int tid = threadIdx.x;
  int j = blockIdx.x, bh = blockIdx.y;
  int s = tid >> 6, lane = tid & 63;
  int lq = lane & 31, hi = lane >> 5;
  int b = bh >> 4, h = bh & 15;
  const u16* src = QKV + (size_t)(b * S_LEN + j * 32 + lq) * QKV_LD
                   + 1024 + h * HDIM + s * 16 + hi * 8;
  bf16x8 v = *(const bf16x8*)src;
  *(bf16x8*)(KP + ((size_t)(bh * 64 + j) * 4 + s) * 512 + lane * 8) = v;
}

// ---------------- V fragment-pack (transposed): VP frag c: d=(c>>1)*32+(lane&31),
// s = j*32 + (c&1)*16 + (lane>>5)*8 + e  -> matches PV A-frag (V^T rows = d). ----------------
__global__ __launch_bounds__(256) void pack_v_kernel(const u16* __restrict__ QKV,
                                                     u16* __restrict__ VP) {
  int tid = threadIdx.x;
  int j = blockIdx.x, bh = blockIdx.y;
  int c = tid >> 6, lane = tid & 63;
  int lq = lane & 31, hi = lane >> 5;
  int b = bh >> 4, h = bh & 15;
  int d = (c >> 1) * 32 + lq;
  int s0 = j * 32 + (c & 1) * 16 + hi * 8;
  const u16* src = QKV + (size_t)(b * S_LEN + s0) * QKV_LD + 2048 + h * HDIM + d;
  u16 tmp[8];
#pragma unroll
  for (int e = 0; e < 8; ++e) tmp[e] = src[(size_t)e * QKV_LD];
  *(bf16x8*)(VP + ((size_t)(bh * 64 + j) * 4 + c) * 512 + lane * 8) = *(bf16x8*)tmp;
}

// ---------------- bf16 GEMM: C[M][ldc] = A[M][1024] * Bt[N][1024]^T ----------------
template <int EPI>  // 0: bf16 C, 1: fp32 C + bias
__global__ __launch_bounds__(256) void gemm_bt_kernel(
    const u16* __restrict__ A, const u16* __restrict__ Bt,
    void* __restrict__ Cv, const float* __restrict__ bias, int ldc) {
  __shared__ u16 lA[128 * 32];
  __shared__ u16 lB[128 * 32];
  const int tid = threadIdx.x, wid = tid >> 6, lane = tid & 63;
  const int bm = blockIdx.y, bn = blockIdx.x;
  const int fr = lane & 15, fq = lane >> 4;
  const int r0 = wid * 32;
  const int srow = lane >> 2, scol = (lane & 3) * 8;
  const u16* gA = A + (size_t)(bm * 128 + r0 + srow) * 1024 + scol;
  const u16* gB = Bt + (size_t)(bn * 128 + r0 + srow) * 1024 + scol;
  u16* lA0 = &lA[r0 * 32];
  u16* lB0 = &lB[r0 * 32];

  f32x4 acc[4][4] = {};
  const int wm = (wid >> 1) * 64, wn = (wid & 1) * 64;

  for (int k0 = 0; k0 < 1024; k0 += 32) {
    gload_lds16(gA + k0,             lA0);
    gload_lds16(gA + k0 + 16 * 1024, lA0 + 16 * 32);
    gload_lds16(gB + k0,             lB0);
    gload_lds16(gB + k0 + 16 * 1024, lB0 + 16 * 32);
    __syncthreads();
    bf16x8 fa[4], fb[4];
#pragma unroll
    for (int i = 0; i < 4; i++) {
      fa[i] = *(const bf16x8*)&lA[(wm + i * 16 + fr) * 32 + fq * 8];
      fb[i] = *(const bf16x8*)&lB[(wn + i * 16 + fr) * 32 + fq * 8];
    }
#pragma unroll
    for (int i = 0; i < 4; i++)
#pragma unroll
      for (int j = 0; j < 4; j++)
        acc[i][j] = __builtin_amdgcn_mfma_f32_16x16x32_bf16(fa[i], fb[j], acc[i][j], 0, 0, 0);
    __syncthreads();
  }

#pragma unroll
  for (int i = 0; i < 4; i++)
#pragma unroll
    for (int j = 0; j < 4; j++)
#pragma unroll
      for (int r = 0; r < 4; r++) {
        int row = bm * 128 + wm + i * 16 + fq * 4 + r;
        int col = bn * 128 + wn + j * 16 + fr;
        if (EPI == 0) {
          ((u16*)Cv)[(size_t)row * ldc + col] = f2bf(acc[i][j][r]);
        } else {
          ((float*)Cv)[(size_t)row * ldc + col] = acc[i][j][r] + bias[col];
        }
      }
}

// ---------------- flash attention (causal), swapped-operand 32x32 MFMA ----------------
// 4 waves/block, wave owns 32 q rows; KV tiles of 32 read from fragment-packed KP/VP
// (perfectly coalesced dwordx4). No LDS, no barriers.
__global__ __launch_bounds__(256) void attn_kernel(
    const u16* __restrict__ QKV, const u16* __restrict__ KP,
    const u16* __restrict__ VP, u16* __restrict__ O) {
  const int tid = threadIdx.x, wid = tid >> 6, lane = tid & 63;
  const int lq = lane & 31, hi = lane >> 5;
  // block swizzle: cluster each head on one XCD, spread qblks across CUs, big tiles first
  int f = blockIdx.x;
  int xcd = f & 7, kk = f >> 3;
  int bh = xcd * 8 + (kk & 7);
  int qblk = 15 - (kk >> 3);
  int b = bh >> 4, h = bh & 15;
  int q0 = qblk * 128 + wid * 32;
  int q = q0 + lq;

  const u16* Qrow = QKV + (size_t)(b * S_LEN + q) * QKV_LD + h * HDIM;
  bf16x8 qf[4];
#pragma unroll
  for (int s = 0; s < 4; s++)
    qf[s] = *(const bf16x8*)(Qrow + s * 16 + hi * 8);

  const bf16x8* KPt = (const bf16x8*)KP + (size_t)bh * 64 * 4 * 64;
  const bf16x8* VPt = (const bf16x8*)VP + (size_t)bh * 64 * 4 * 64;

  f32x16 acc0 = {}, acc1 = {};
  float m = -3.0e38f, l = 0.f;
  const int nt = qblk * 4 + wid + 1;

  for (int t = 0; t < nt; ++t) {
    const int j0 = t * 32;
    const size_t fb = (size_t)t * 4 * 64 + lane;
    bf16x8 kf0 = KPt[fb], kf1 = KPt[fb + 64], kf2 = KPt[fb + 128], kf3 = KPt[fb + 192];
    bf16x8 vf00 = VPt[fb], vf01 = VPt[fb + 64], vf10 = VPt[fb + 128], vf11 = VPt[fb + 192];

    f32x16 sa = {};
    __builtin_amdgcn_s_setprio(1);
    sa = __builtin_amdgcn_mfma_f32_32x32x16_bf16(kf0, qf[0], sa, 0, 0, 0);
    sa = __builtin_amdgcn_mfma_f32_32x32x16_bf16(kf1, qf[1], sa, 0, 0, 0);
    sa = __builtin_amdgcn_mfma_f32_32x32x16_bf16(kf2, qf[2], sa, 0, 0, 0);
    sa = __builtin_amdgcn_mfma_f32_32x32x16_bf16(kf3, qf[3], sa, 0, 0, 0);
    __builtin_amdgcn_s_setprio(0);

    // log2-domain scores: v = S * (1/8 * log2(e))
    float p[16];
#pragma unroll
    for (int r = 0; r < 16; ++r) p[r] = sa[r] * 0.1803368801f;

    if (t == nt - 1) {  // diagonal tile: causal mask
#pragma unroll
      for (int r = 0; r < 16; ++r) {
        int kidx = j0 + (r & 3) + 8 * (r >> 2) + 4 * hi;
        if (kidx > q) p[r] = -3.0e38f;
      }
    }

    // row max: 15-op reg tree + one cross-half exchange
    float x8[8], x4[4], x2[2];
#pragma unroll
    for (int i = 0; i < 8; ++i) x8[i] = fmaxf(p[2 * i], p[2 * i + 1]);
#pragma unroll
    for (int i = 0; i < 4; ++i) x4[i] = fmaxf(x8[2 * i], x8[2 * i + 1]);
    x2[0] = fmaxf(x4[0], x4[1]); x2[1] = fmaxf(x4[2], x4[3]);
    float pm = fmaxf(x2[0], x2[1]);
    pm = fmaxf(pm, __shfl_xor(pm, 32));

    // defer-max (THR = 8 nats = 11.54 log2 units)
    if (__any(pm > m + 11.5f)) {
      float mn = fmaxf(m, pm);
      float sc = EXP2(m - mn);
      l *= sc;
#pragma unroll
      for (int r = 0; r < 16; ++r) { acc0[r] *= sc; acc1[r] *= sc; }
      m = mn;
    }

    float rs = 0.f;
#pragma unroll
    for (int r = 0; r < 16; ++r) { p[r] = EXP2(p[r] - m); rs += p[r]; }
    rs += __shfl_xor(rs, 32);
    l += rs;

    // pack P -> bf16 B-frags: cvt_pk pairs + permlane32 half-swaps
    unsigned c0 = cvtpk(p[0],  p[1]),  c1 = cvtpk(p[2],  p[3]);
    unsigned c2 = cvtpk(p[4],  p[5]),  c3 = cvtpk(p[6],  p[7]);
    unsigned c4 = cvtpk(p[8],  p[9]),  c5 = cvtpk(p[10], p[11]);
    unsigned c6 = cvtpk(p[12], p[13]), c7 = cvtpk(p[14], p[15]);
    perm32swap(c0, c2); perm32swap(c1, c3);
    perm32swap(c4, c6); perm32swap(c5, c7);
    union U4 { unsigned u[4]; bf16x8 v; } F0, F1;
    F0.u[0] = c0; F0.u[1] = c1; F0.u[2] = c2; F0.u[3] = c3;
    F1.u[0] = c4; F1.u[1] = c5; F1.u[2] = c6; F1.u[3] = c7;

    __builtin_amdgcn_s_setprio(1);
    acc0 = __builtin_amdgcn_mfma_f32_32x32x16_bf16(vf00, F0.v, acc0, 0, 0, 0);
    acc0 = __builtin_amdgcn_mfma_f32_32x32x16_bf16(vf01, F1.v, acc0, 0, 0, 0);
    acc1 = __builtin_amdgcn_mfma_f32_32x32x16_bf16(vf10, F0.v, acc1, 0, 0, 0);
    acc1 = __builtin_amdgcn_mfma_f32_32x32x16_bf16(vf11, F1.v, acc1, 0, 0, 0);
    __builtin_amdgcn_s_setprio(0);
  }

  float inv = 1.f / l;
  u16* Orow = O + (size_t)(b * S_LEN + q) * D_DIM + h * HDIM;
#pragma unroll
  for (int g = 0; g < 4; ++g) {
    ushort4 o4;
    o4.x = f2bf(acc0[g * 4 + 0] * inv);
    o4.y = f2bf(acc0[g * 4 + 1] * inv);
    o4.z = f2bf(acc0[g * 4 + 2] * inv);
    o4.w = f2bf(acc0[g * 4 + 3] * inv);
    *(ushort4*)(Orow + 8 * g + 4 * hi) = o4;
  }
#pragma unroll
  for (int g = 0; g < 4; ++g) {
    ushort4 o4;
    o4.x = f2bf(acc1[g * 4 + 0] * inv);
    o4.y = f2bf(acc1[g * 4 + 1] * inv);
    o4.z = f2bf(acc1[g * 4 + 2] * inv);
    o4.w = f2bf(acc1[g * 4 + 3] * inv);
    *(ushort4*)(Orow + 32 + 8 * g + 4 * hi) = o4;
  }
}

// ---------------- launcher ----------------
extern "C" void kernel_launch(void* const* d_in, const int* in_sizes, int n_in,
                              void* d_out, int out_size, void* d_ws, size_t ws_size,
                              hipStream_t stream) {
  const float* x  = (const float*)d_in[0];
  const float* wq = (const float*)d_in[1];
  const float* wk = (const float*)d_in[2];
  const float* wv = (const float*)d_in[3];
  const float* wo = (const float*)d_in[4];
  const float* ob = (const float*)d_in[5];
  float* out = (float*)d_out;

  char* ws = (char*)d_ws;
  // slot A (0-16MB): Xb until QKV GEMM, then reused as Ab (attn output)
  u16* Xb    = (u16*)(ws);
  u16* Ab    = (u16*)(ws);
  u16* QKV   = (u16*)(ws + (size_t)16 * 1024 * 1024);   // 48 MB
  u16* KPb   = (u16*)(ws + (size_t)64 * 1024 * 1024);   // 16 MB
  u16* VPb   = (u16*)(ws + (size_t)80 * 1024 * 1024);   // 16 MB
  u16* WqkvT = (u16*)(ws + (size_t)96 * 1024 * 1024);   // 6 MB
  u16* WoT   = (u16*)(ws + (size_t)102 * 1024 * 1024);  // 2 MB

  cvt_x_kernel<<<(MROWS * D_DIM / 4) / 256, 256, 0, stream>>>(x, Xb, MROWS * D_DIM / 4);

  dim3 tb(32, 8);
  transpose_w_kernel<<<dim3(32, 32), tb, 0, stream>>>(wq, WqkvT);
  transpose_w_kernel<<<dim3(32, 32), tb, 0, stream>>>(wk, WqkvT + 1024 * 1024);
  transpose_w_kernel<<<dim3(32, 32), tb, 0, stream>>>(wv, WqkvT + 2 * 1024 * 1024);
  transpose_w_kernel<<<dim3(32, 32), tb, 0, stream>>>(wo, WoT);

  // fused QKV projection: [8192,1024] x [1024,3072] -> QKV [8192,3072]
  gemm_bt_kernel<0><<<dim3(QKV_LD / 128, MROWS / 128), 256, 0, stream>>>(
      Xb, WqkvT, QKV, nullptr, QKV_LD);

  pack_k_kernel<<<dim3(64, 64), 256, 0, stream>>>(QKV, KPb);
  pack_v_kernel<<<dim3(64, 64), 256, 0, stream>>>(QKV, VPb);

  attn_kernel<<<dim3(1024), 256, 0, stream>>>(QKV, KPb, VPb, Ab);

  gemm_bt_kernel<1><<<dim3(D_DIM / 128, MROWS / 128), 256, 0, stream>>>(
      Ab, WoT, out, ob, D_DIM);
}